// Round 4
// baseline (123.510 us; speedup 1.0000x reference)
//
#include <hip/hip_runtime.h>

#define NB 2
#define NN 30
#define NC 320
#define NM 31
#define HW 4096
#define FMIN_F (-3.40282346638528859812e+38f)

typedef float nfloat4 __attribute__((ext_vector_type(4)));

// workspace layout (float offsets)
#define OFF_ASUM   0         // [2*4096]  sum_c attn
#define OFF_AWRED  8192      // [2*4096]  sum_c attn*w_reduce
#define OFF_GS     16384     // [2*4096]  sum_c nhs   (g_s image, 64x64 per b)
#define OFF_GW     24576     // [2*4096]  sum_c nhs*w_reduce (g_w image)
#define OFF_RS     32768     // [2*30*1024] per-cell channel-sum of roi_feats
#define OFF_RW     94208     // [2*30*1024] per-cell w_reduce-dot of roi_feats
#define OFF_MP     155648    // [64] unsigned: per-(b,m) max, monotone-encoded (plain stores)
// NOTES (hard-won):
// - inter-block data handoff must cross a KERNEL BOUNDARY; per-block
//   __threadfence() = per-XCD L2 writeback; 7680 of them cost +130us (r1).
// - contended device-scope atomics to shared MP slots + an extra memset
//   dispatch cost ~+12us (r2). MP: plain stores, single writer per slot.
// - iteration floor ~95-100us = 44.5us ws-poison fill + ~130 tiny restore
//   dispatches (fill IDs ~135-190 apart). Only ~20-25us is our kernels.
// - r4: roi_feats round-trip deleted. rs/rw grids = 9-tap stencil on
//   channel-reduced g images (linearity); unpool = separable 1-D weight
//   vectors applied directly to nhs (exact reference math, fp32).

#define GRID_RED 3277                  // ceil(2*8192/5) row-waves, 5/block

__device__ __forceinline__ void get_box(const float* boxes, int b, int n,
                                        float& x1, float& y1, float& bw, float& bh) {
    const float* p = boxes + (b * NN + n) * 4;
    float X1 = p[0] * 64.0f - 0.5f;
    float Y1 = p[1] * 64.0f - 0.5f;
    float X2 = p[2] * 64.0f - 0.5f;
    float Y2 = p[3] * 64.0f - 0.5f;
    x1 = X1; y1 = Y1;
    bw = (X2 - X1) / 32.0f;
    bh = (Y2 - Y1) / 32.0f;
}

// monotone float <-> uint encoding (k_final reads MP uniformly)
__device__ __forceinline__ unsigned encf(float f) {
    unsigned u = __float_as_uint(f);
    return (u & 0x80000000u) ? ~u : (u | 0x80000000u);
}
__device__ __forceinline__ float decf(unsigned e) {
    unsigned u = (e & 0x80000000u) ? (e & 0x7fffffffu) : ~e;
    return __uint_as_float(u);
}

// Kernel 1: channel reductions, one wave per row.
//   rows [0, 16384): first half = attn -> asum/awred, second = nhs -> gs/gw.
__global__ void k_reduce(const float* __restrict__ nhs, const float* __restrict__ attn,
                         const float* __restrict__ wred, float* __restrict__ ws) {
    int wave = threadIdx.x >> 6;
    int lane = threadIdx.x & 63;
    int row = blockIdx.x * 5 + wave;
    if (row >= 2 * NB * HW) return;
    const float* src;
    float *d0, *d1;
    if (row < NB * HW) {
        src = attn + (size_t)row * NC;
        d0 = ws + OFF_ASUM + row;
        d1 = ws + OFF_AWRED + row;
    } else {
        int r = row - NB * HW;
        src = nhs + (size_t)r * NC;
        d0 = ws + OFF_GS + r;
        d1 = ws + OFF_GW + r;
    }
    const float4* a4 = (const float4*)src;
    const float4* w4 = (const float4*)wred;
    float4 wv = w4[lane];
    float4 av = a4[lane];
    float s_a = av.x + av.y + av.z + av.w;
    float w_a = av.x * wv.x + av.y * wv.y + av.z * wv.z + av.w * wv.w;
    if (lane < 16) {
        float4 wv2 = w4[lane + 64];
        float4 av2 = a4[lane + 64];
        s_a += av2.x + av2.y + av2.z + av2.w;
        w_a += av2.x * wv2.x + av2.y * wv2.y + av2.z * wv2.z + av2.w * wv2.w;
    }
#pragma unroll
    for (int off = 32; off > 0; off >>= 1) {
        s_a += __shfl_down(s_a, off, 64);
        w_a += __shfl_down(w_a, off, 64);
    }
    if (lane == 0) {
        d0[0] = s_a;
        d1[0] = w_a;
    }
}

// Kernel 2: per-ROI rs/rw grids from g images (LDS-staged) + fw max + MP.
//   blocks 0..59  : one per (b,n). Masked -> MP = encf(0) (fw==0 everywhere).
//                   Active -> compute 1024 cells (9-tap folded stencil on g),
//                   write rs/rw, then bbox-restricted fw max scan (exact
//                   per-pixel validity; clamp at 0: invalid pixels contribute
//                   fw=0 and always exist since boxes are <=26px wide).
//   blocks 60..61 : m=0 per b -> exact max over the 4096 awred values (raw).
__global__ void k_grids(const float* __restrict__ boxes, const int* __restrict__ masks,
                        float* __restrict__ ws) {
    __shared__ float gsm[4096], gwm[4096];
    __shared__ float rwsm[1024];
    __shared__ float red[4];
    int tid = threadIdx.x;
    int bm = blockIdx.x;
    unsigned* MP = (unsigned*)(ws + OFF_MP);

    if (bm >= NB * NN) {               // m = 0 rows
        int b = bm - NB * NN;
        const float* aw = ws + OFF_AWRED + b * HW;
        float lm = FMIN_F;
        for (int i = tid; i < HW; i += 256) lm = fmaxf(lm, aw[i]);
#pragma unroll
        for (int off = 32; off > 0; off >>= 1)
            lm = fmaxf(lm, __shfl_down(lm, off, 64));
        if ((tid & 63) == 0) red[tid >> 6] = lm;
        __syncthreads();
        if (tid == 0) {
            float mx = fmaxf(fmaxf(red[0], red[1]), fmaxf(red[2], red[3]));
            MP[b * NM] = encf(mx);
        }
        return;
    }

    int b = bm / NN, n = bm % NN;
    if (masks[b * NN + n] == 0) {
        if (tid == 0) MP[b * NM + 1 + n] = encf(0.0f);
        return;
    }
    const float* gs = ws + OFF_GS + b * HW;
    const float* gw = ws + OFF_GW + b * HW;
    for (int i = tid; i < 4096; i += 256) {
        gsm[i] = gs[i];
        gwm[i] = gw[i];
    }
    float x1, y1, bw, bh;
    get_box(boxes, b, n, x1, y1, bw, bh);
    __syncthreads();

    float* RS = ws + OFF_RS + (b * NN + n) * 1024;
    float* RW = ws + OFF_RW + (b * NN + n) * 1024;
    for (int c = tid; c < 1024; c += 256) {
        int q = c & 31, p = c >> 5;
        float W[9] = {0.f,0.f,0.f,0.f,0.f,0.f,0.f,0.f,0.f};
        float wys[4], wxs[4];
        int iy0s[4], ix0s[4];
        int iymin = 64, ixmin = 64;
#pragma unroll
        for (int s_ = 0; s_ < 4; s_++) {
            int di = s_ >> 1, dj = s_ & 1;
            float y = y1 + ((float)p + 0.25f + 0.5f * (float)di) * bh;
            float x = x1 + ((float)q + 0.25f + 0.5f * (float)dj) * bw;
            float yc = fminf(fmaxf(y, 0.0f), 63.0f);
            float xc = fminf(fmaxf(x, 0.0f), 63.0f);
            int iy0 = (int)floorf(yc), ix0 = (int)floorf(xc);
            wys[s_] = yc - (float)iy0;
            wxs[s_] = xc - (float)ix0;
            iy0s[s_] = iy0; ix0s[s_] = ix0;
            iymin = min(iymin, iy0); ixmin = min(ixmin, ix0);
        }
#pragma unroll
        for (int s_ = 0; s_ < 4; s_++) {
            float wy = wys[s_], wx = wxs[s_];
            int dy = iy0s[s_] - iymin;
            int dx = ix0s[s_] - ixmin;
            bool yt = (iy0s[s_] == 63);
            bool xt = (ix0s[s_] == 63);
            float ay0 = yt ? 1.0f : (1.0f - wy);
            float ay1 = yt ? 0.0f : wy;
            float ax0 = xt ? 1.0f : (1.0f - wx);
            float ax1 = xt ? 0.0f : wx;
            float r0 = dy ? 0.0f : ay0;
            float r1 = dy ? ay0  : ay1;
            float r2 = dy ? ay1  : 0.0f;
            float c0 = dx ? 0.0f : ax0;
            float c1 = dx ? ax0  : ax1;
            float c2 = dx ? ax1  : 0.0f;
            W[0] += r0 * c0; W[1] += r0 * c1; W[2] += r0 * c2;
            W[3] += r1 * c0; W[4] += r1 * c1; W[5] += r1 * c2;
            W[6] += r2 * c0; W[7] += r2 * c1; W[8] += r2 * c2;
        }
        int base = iymin * 64 + ixmin;
        float ss = 0.f, ww = 0.f;
#pragma unroll
        for (int k = 0; k < 9; k++) {
            if (W[k] != 0.0f) {
                float wk = W[k] * 0.25f;
                int off = base + (k / 3) * 64 + (k % 3);
                ss += wk * gsm[off];
                ww += wk * gwm[off];
            }
        }
        RS[c] = ss;
        RW[c] = ww;
        rwsm[c] = ww;
    }
    __syncthreads();

    // fw max over valid pixels (bbox-restricted scan, rw grid in LDS)
    int h0  = max(0, (int)floorf(y1 - 0.5f * bh) - 1);
    int h1  = min(63, (int)ceilf(y1 + 32.5f * bh) + 1);
    int wq0 = max(0, (int)floorf(x1 - 0.5f * bw) - 1);
    int wq1 = min(63, (int)ceilf(x1 + 32.5f * bw) + 1);
    int Wd = wq1 - wq0 + 1;
    int tot = Wd * (h1 - h0 + 1);
    float lm = FMIN_F;
    for (int i = tid; i < tot; i += 256) {
        int h  = h0 + i / Wd;
        int wp = wq0 + i % Wd;
        float ry = ((float)h - y1) / bh - 0.5f;
        float rx = ((float)wp - x1) / bw - 0.5f;
        if (ry > -1.0f && ry < 32.0f && rx > -1.0f && rx < 32.0f) {
            float yc = fminf(fmaxf(ry, 0.0f), 31.0f);
            float xc = fminf(fmaxf(rx, 0.0f), 31.0f);
            int iy0 = (int)floorf(yc), ix0 = (int)floorf(xc);
            int iy1 = min(iy0 + 1, 31), ix1 = min(ix0 + 1, 31);
            float wy = yc - (float)iy0, wx = xc - (float)ix0;
            float fwv = (1.f - wy) * (1.f - wx) * rwsm[iy0 * 32 + ix0]
                      + (1.f - wy) * wx        * rwsm[iy0 * 32 + ix1]
                      + wy * (1.f - wx)        * rwsm[iy1 * 32 + ix0]
                      + wy * wx                * rwsm[iy1 * 32 + ix1];
            lm = fmaxf(lm, fwv);
        }
    }
#pragma unroll
    for (int off = 32; off > 0; off >>= 1)
        lm = fmaxf(lm, __shfl_down(lm, off, 64));
    if ((tid & 63) == 0) red[tid >> 6] = lm;
    __syncthreads();
    if (tid == 0) {
        float mx = fmaxf(fmaxf(red[0], red[1]), fmaxf(red[2], red[3]));
        MP[b * NM + 1 + n] = encf(fmaxf(mx, 0.0f));
    }
}

// Kernel 3: fused MLP + inline-z softmax + final gather. The unpool value is
// recomputed DIRECTLY from nhs with separable 1-D weight vectors:
//   unpool(c) = sum_r WY[r] * sum_cc WX[cc] * fmap(c, rb+r, cb+cc)
// where WY/WX fold the outer bilinear (2 cells/axis) x subsample avg
// (2/axis) x inner bilinear (2 taps/axis) with per-position clamping --
// exact reference math in fp32. block = 8 pixels x 40 lanes; 8 ch/thread.
__global__ void k_final(const float* __restrict__ nhs, const float* __restrict__ attn,
                        const float* __restrict__ boxes, const int* __restrict__ masks,
                        const int* __restrict__ perm,
                        const float* __restrict__ w1, const float* __restrict__ b1,
                        const float* __restrict__ w2, const float* __restrict__ b2,
                        const float* __restrict__ ws, float* __restrict__ out) {
    __shared__ float mpg[NM], hb[NM], scal[32], wbuf[8][32];
    __shared__ int acnt[8];
    __shared__ unsigned char alist[8][NN];
    int t = threadIdx.x;
    int idx0 = blockIdx.x * 8;         // all 8 pixels share the same b
    int b = idx0 >> 12;

    if (t < 8) acnt[t] = 0;
    if (t < NM) {
        unsigned e = ((const unsigned*)(ws + OFF_MP))[b * NM + ((t == 0) ? 0 : 1 + perm[t - 1])];
        mpg[t] = decf(e);
    }
    __syncthreads();
    if (t < NM) {
        float a = b1[t];
#pragma unroll
        for (int k = 0; k < NM; k++) a += mpg[k] * w1[k * NM + t];
        hb[t] = fmaxf(a, 0.0f);
    }
    __syncthreads();
    if (t < NM) {
        float a = b2[t];
#pragma unroll
        for (int k = 0; k < NM; k++) a += hb[k] * w2[k * NM + t];
        float sig = 1.0f / (1.0f + expf(-a));
        if (t == 0) scal[0] = sig;
        else        scal[1 + perm[t - 1]] = sig;
    }
    __syncthreads();

    // softmax with inline z: one thread per (pixel, m)
    if (t < 256) {
        int pg = t >> 5, m = t & 31;
        int pix = (idx0 + pg) & 4095;
        float zz = FMIN_F;
        if (m == 0) {
            float fwv = ws[OFF_AWRED + b * HW + pix];
            bool fg = (ws[OFF_ASUM + b * HW + pix] != 0.0f);
            zz = fg ? fwv * scal[0] : FMIN_F;
        } else if (m < NM) {
            int n = m - 1;
            if (masks[b * NN + n]) {
                float x1, y1, bw, bh;
                get_box(boxes, b, n, x1, y1, bw, bh);
                int h = pix >> 6, wp = pix & 63;
                float ry = ((float)h - y1) / bh - 0.5f;
                float rx = ((float)wp - x1) / bw - 0.5f;
                bool valid = (ry > -1.0f) && (ry < 32.0f) && (rx > -1.0f) && (rx < 32.0f);
                if (valid) {
                    float yc = fminf(fmaxf(ry, 0.0f), 31.0f);
                    float xc = fminf(fmaxf(rx, 0.0f), 31.0f);
                    int iy0 = (int)floorf(yc), ix0 = (int)floorf(xc);
                    int iy1 = min(iy0 + 1, 31), ix1 = min(ix0 + 1, 31);
                    float wy = yc - (float)iy0, wx = xc - (float)ix0;
                    float w00 = (1.f - wy) * (1.f - wx), w01 = (1.f - wy) * wx;
                    float w10 = wy * (1.f - wx), w11 = wy * wx;
                    const float* rw = ws + OFF_RW + (b * NN + n) * 1024;
                    const float* rs = ws + OFF_RS + (b * NN + n) * 1024;
                    float fwv = w00 * rw[iy0 * 32 + ix0] + w01 * rw[iy0 * 32 + ix1]
                              + w10 * rw[iy1 * 32 + ix0] + w11 * rw[iy1 * 32 + ix1];
                    float su  = w00 * rs[iy0 * 32 + ix0] + w01 * rs[iy0 * 32 + ix1]
                              + w10 * rs[iy1 * 32 + ix0] + w11 * rs[iy1 * 32 + ix1];
                    if (su != 0.0f) zz = fwv * scal[m];
                }
            }
        }
        float mx = zz;
#pragma unroll
        for (int off = 16; off > 0; off >>= 1)
            mx = fmaxf(mx, __shfl_xor(mx, off, 64));
        float e = (m < NM) ? expf(zz - mx) : 0.0f;
        float s = e;
#pragma unroll
        for (int off = 16; off > 0; off >>= 1)
            s += __shfl_xor(s, off, 64);
        if (m < NM) {
            float w = e / s;
            wbuf[pg][m] = w;
            if (m >= 1 && w != 0.0f) {
                int pos = atomicAdd(&acnt[pg], 1);
                alist[pg][pos] = (unsigned char)(m - 1);
            }
        }
    }
    __syncthreads();

    int pid = t / 40;
    int v = t - pid * 40;
    int idx = idx0 + pid;
    int pix = idx & 4095;
    int h = pix >> 6, wp = pix & 63;
    float w0 = wbuf[pid][0];
    const float4* at4 = (const float4*)attn;
    float4 a0 = at4[(size_t)idx * 80 + v * 2];
    float4 a1 = at4[(size_t)idx * 80 + v * 2 + 1];
    float4 acc0, acc1;
    acc0.x = a0.x * w0; acc0.y = a0.y * w0; acc0.z = a0.z * w0; acc0.w = a0.w * w0;
    acc1.x = a1.x * w0; acc1.y = a1.y * w0; acc1.z = a1.z * w0; acc1.w = a1.w * w0;
    const float4* fb4 = (const float4*)(nhs + (size_t)b * HW * NC);
    int na = acnt[pid];
    for (int k = 0; k < na; k++) {
        int n = alist[pid][k];
        float wn = wbuf[pid][n + 1];
        float x1, y1, bw, bh;
        get_box(boxes, b, n, x1, y1, bw, bh);
        float ry = ((float)h - y1) / bh - 0.5f;
        float rx = ((float)wp - x1) / bw - 0.5f;
        float yc = fminf(fmaxf(ry, 0.0f), 31.0f);
        float xc = fminf(fmaxf(rx, 0.0f), 31.0f);
        int iy0 = (int)floorf(yc), ix0 = (int)floorf(xc);
        int iy1 = min(iy0 + 1, 31), ix1 = min(ix0 + 1, 31);
        float fy = yc - (float)iy0, fx = xc - (float)ix0;

        // separable weight vectors (4 slots each; taps span <=3 rows/cols)
        float ya00 = fminf(fmaxf(y1 + ((float)iy0 + 0.25f) * bh, 0.f), 63.f);
        float ya01 = fminf(fmaxf(y1 + ((float)iy0 + 0.75f) * bh, 0.f), 63.f);
        float ya10 = fminf(fmaxf(y1 + ((float)iy1 + 0.25f) * bh, 0.f), 63.f);
        float ya11 = fminf(fmaxf(y1 + ((float)iy1 + 0.75f) * bh, 0.f), 63.f);
        float xa00 = fminf(fmaxf(x1 + ((float)ix0 + 0.25f) * bw, 0.f), 63.f);
        float xa01 = fminf(fmaxf(x1 + ((float)ix0 + 0.75f) * bw, 0.f), 63.f);
        float xa10 = fminf(fmaxf(x1 + ((float)ix1 + 0.25f) * bw, 0.f), 63.f);
        float xa11 = fminf(fmaxf(x1 + ((float)ix1 + 0.75f) * bw, 0.f), 63.f);
        int rb = (int)floorf(ya00);    // positions are monotone -> min first
        int cb = (int)floorf(xa00);
        float wyv[4] = {0.f,0.f,0.f,0.f};
        float wxv[4] = {0.f,0.f,0.f,0.f};
        float cy0 = 0.5f * (1.0f - fy), cy1 = 0.5f * fy;
        float cx0 = 0.5f * (1.0f - fx), cx1 = 0.5f * fx;
        {
            int i; float f;
            i = (int)floorf(ya00); f = ya00 - (float)i;
            wyv[i - rb] += cy0 * (1.f - f); wyv[min(i + 1, 63) - rb] += cy0 * f;
            i = (int)floorf(ya01); f = ya01 - (float)i;
            wyv[i - rb] += cy0 * (1.f - f); wyv[min(i + 1, 63) - rb] += cy0 * f;
            i = (int)floorf(ya10); f = ya10 - (float)i;
            wyv[i - rb] += cy1 * (1.f - f); wyv[min(i + 1, 63) - rb] += cy1 * f;
            i = (int)floorf(ya11); f = ya11 - (float)i;
            wyv[i - rb] += cy1 * (1.f - f); wyv[min(i + 1, 63) - rb] += cy1 * f;
            i = (int)floorf(xa00); f = xa00 - (float)i;
            wxv[i - cb] += cx0 * (1.f - f); wxv[min(i + 1, 63) - cb] += cx0 * f;
            i = (int)floorf(xa01); f = xa01 - (float)i;
            wxv[i - cb] += cx0 * (1.f - f); wxv[min(i + 1, 63) - cb] += cx0 * f;
            i = (int)floorf(xa10); f = xa10 - (float)i;
            wxv[i - cb] += cx1 * (1.f - f); wxv[min(i + 1, 63) - cb] += cx1 * f;
            i = (int)floorf(xa11); f = xa11 - (float)i;
            wxv[i - cb] += cx1 * (1.f - f); wxv[min(i + 1, 63) - cb] += cx1 * f;
        }
#pragma unroll
        for (int r = 0; r < 4; r++) {
            float wy = wyv[r];
            if (wy == 0.f) continue;
            int rowoff = (rb + r) * 64 + cb;
#pragma unroll
            for (int cc = 0; cc < 4; cc++) {
                float wgt = wy * wxv[cc];
                if (wgt == 0.f) continue;
                wgt *= wn;
                int off = (rowoff + cc) * 80 + v * 2;
                float4 f0 = fb4[off];
                float4 f1 = fb4[off + 1];
                acc0.x += wgt * f0.x; acc0.y += wgt * f0.y;
                acc0.z += wgt * f0.z; acc0.w += wgt * f0.w;
                acc1.x += wgt * f1.x; acc1.y += wgt * f1.y;
                acc1.z += wgt * f1.z; acc1.w += wgt * f1.w;
            }
        }
    }
    nfloat4 nv0 = { acc0.x, acc0.y, acc0.z, acc0.w };
    nfloat4 nv1 = { acc1.x, acc1.y, acc1.z, acc1.w };
    __builtin_nontemporal_store(nv0, ((nfloat4*)out) + (size_t)idx * 80 + v * 2);
    __builtin_nontemporal_store(nv1, ((nfloat4*)out) + (size_t)idx * 80 + v * 2 + 1);
}

extern "C" void kernel_launch(void* const* d_in, const int* in_sizes, int n_in,
                              void* d_out, int out_size, void* d_ws, size_t ws_size,
                              hipStream_t stream) {
    const float* nhs   = (const float*)d_in[0];
    const float* attn  = (const float*)d_in[1];
    const float* boxes = (const float*)d_in[2];
    const int*   masks = (const int*)d_in[3];
    const int*   perm  = (const int*)d_in[4];
    const float* wred  = (const float*)d_in[5];
    const float* w1    = (const float*)d_in[6];
    const float* b1    = (const float*)d_in[7];
    const float* w2    = (const float*)d_in[8];
    const float* b2    = (const float*)d_in[9];
    float* out = (float*)d_out;
    float* ws = (float*)d_ws;

    k_reduce<<<GRID_RED, 320, 0, stream>>>(nhs, attn, wred, ws);
    k_grids<<<NB * NN + NB, 256, 0, stream>>>(boxes, masks, ws);
    k_final<<<NB * HW / 8, 320, 0, stream>>>(nhs, attn, boxes, masks, perm,
                                             w1, b1, w2, b2, ws, out);
}

// Round 5
// 116.803 us; speedup vs baseline: 1.0574x; 1.0574x over previous
//
#include <hip/hip_runtime.h>

#define NB 2
#define NN 30
#define NC 320
#define NM 31
#define HW 4096
#define FMIN_F (-3.40282346638528859812e+38f)

typedef float nfloat4 __attribute__((ext_vector_type(4)));

// workspace layout (float offsets)
#define OFF_ASUM   0         // [2*4096]  sum_c attn
#define OFF_AWRED  8192      // [2*4096]  sum_c attn*w_reduce
#define OFF_GS     16384     // [2*4096]  sum_c nhs   (g_s image, 64x64 per b)
#define OFF_GW     24576     // [2*4096]  sum_c nhs*w_reduce (g_w image)
#define OFF_RS     32768     // [2*30*1024] per-cell channel-sum of roi_feats
#define OFF_RW     94208     // [2*30*1024] per-cell w_reduce-dot of roi_feats
#define OFF_MP     155648    // [64] unsigned: per-(b,m) max, monotone-encoded (plain stores)
// NOTES (hard-won):
// - inter-block data handoff must cross a KERNEL BOUNDARY; per-block
//   __threadfence() = per-XCD L2 writeback; 7680 of them cost +130us (r1).
// - contended device-scope atomics to shared MP slots + extra memset dispatch
//   cost ~+12us (r2). MP: plain stores, single writer per slot.
// - iteration floor ~100us: TWO 256MiB poison fills (~45us each, adjacent
//   dispatch ords) + ~130 tiny restore dispatches. Our kernels ~20us.
// - r4: roi_feats round-trip deleted (grids from channel-reduced g images by
//   linearity; unpool = separable 1-D weights applied to nhs, exact fp32).
// - r5: separable fold moved to z-phase, named scalars (runtime-indexed
//   local arrays -> scratch, rule: never index locals at runtime).

#define GRID_RED 3277                  // ceil(2*8192/5) row-waves, 5/block

__device__ __forceinline__ void get_box(const float* boxes, int b, int n,
                                        float& x1, float& y1, float& bw, float& bh) {
    const float* p = boxes + (b * NN + n) * 4;
    float X1 = p[0] * 64.0f - 0.5f;
    float Y1 = p[1] * 64.0f - 0.5f;
    float X2 = p[2] * 64.0f - 0.5f;
    float Y2 = p[3] * 64.0f - 0.5f;
    x1 = X1; y1 = Y1;
    bw = (X2 - X1) / 32.0f;
    bh = (Y2 - Y1) / 32.0f;
}

// monotone float <-> uint encoding (k_final reads MP uniformly)
__device__ __forceinline__ unsigned encf(float f) {
    unsigned u = __float_as_uint(f);
    return (u & 0x80000000u) ? ~u : (u | 0x80000000u);
}
__device__ __forceinline__ float decf(unsigned e) {
    unsigned u = (e & 0x80000000u) ? (e & 0x7fffffffu) : ~e;
    return __uint_as_float(u);
}

// Kernel 1: channel reductions, one wave per row.
//   rows [0, 16384): first half = attn -> asum/awred, second = nhs -> gs/gw.
__global__ void k_reduce(const float* __restrict__ nhs, const float* __restrict__ attn,
                         const float* __restrict__ wred, float* __restrict__ ws) {
    int wave = threadIdx.x >> 6;
    int lane = threadIdx.x & 63;
    int row = blockIdx.x * 5 + wave;
    if (row >= 2 * NB * HW) return;
    const float* src;
    float *d0, *d1;
    if (row < NB * HW) {
        src = attn + (size_t)row * NC;
        d0 = ws + OFF_ASUM + row;
        d1 = ws + OFF_AWRED + row;
    } else {
        int r = row - NB * HW;
        src = nhs + (size_t)r * NC;
        d0 = ws + OFF_GS + r;
        d1 = ws + OFF_GW + r;
    }
    const float4* a4 = (const float4*)src;
    const float4* w4 = (const float4*)wred;
    float4 wv = w4[lane];
    float4 av = a4[lane];
    float s_a = av.x + av.y + av.z + av.w;
    float w_a = av.x * wv.x + av.y * wv.y + av.z * wv.z + av.w * wv.w;
    if (lane < 16) {
        float4 wv2 = w4[lane + 64];
        float4 av2 = a4[lane + 64];
        s_a += av2.x + av2.y + av2.z + av2.w;
        w_a += av2.x * wv2.x + av2.y * wv2.y + av2.z * wv2.z + av2.w * wv2.w;
    }
#pragma unroll
    for (int off = 32; off > 0; off >>= 1) {
        s_a += __shfl_down(s_a, off, 64);
        w_a += __shfl_down(w_a, off, 64);
    }
    if (lane == 0) {
        d0[0] = s_a;
        d1[0] = w_a;
    }
}

// Kernel 2: per-ROI rs/rw grids from g images (LDS-staged) + fw max + MP.
//   blocks 0..59  : one per (b,n). Masked -> MP = encf(0) (fw==0 everywhere).
//   blocks 60..61 : m=0 per b -> exact max over the 4096 awred values (raw).
__global__ void k_grids(const float* __restrict__ boxes, const int* __restrict__ masks,
                        float* __restrict__ ws) {
    __shared__ float gsm[4096], gwm[4096];
    __shared__ float rwsm[1024];
    __shared__ float red[4];
    int tid = threadIdx.x;
    int bm = blockIdx.x;
    unsigned* MP = (unsigned*)(ws + OFF_MP);

    if (bm >= NB * NN) {               // m = 0 rows
        int b = bm - NB * NN;
        const float* aw = ws + OFF_AWRED + b * HW;
        float lm = FMIN_F;
        for (int i = tid; i < HW; i += 256) lm = fmaxf(lm, aw[i]);
#pragma unroll
        for (int off = 32; off > 0; off >>= 1)
            lm = fmaxf(lm, __shfl_down(lm, off, 64));
        if ((tid & 63) == 0) red[tid >> 6] = lm;
        __syncthreads();
        if (tid == 0) {
            float mx = fmaxf(fmaxf(red[0], red[1]), fmaxf(red[2], red[3]));
            MP[b * NM] = encf(mx);
        }
        return;
    }

    int b = bm / NN, n = bm % NN;
    if (masks[b * NN + n] == 0) {
        if (tid == 0) MP[b * NM + 1 + n] = encf(0.0f);
        return;
    }
    const float* gs = ws + OFF_GS + b * HW;
    const float* gw = ws + OFF_GW + b * HW;
    for (int i = tid; i < 4096; i += 256) {
        gsm[i] = gs[i];
        gwm[i] = gw[i];
    }
    float x1, y1, bw, bh;
    get_box(boxes, b, n, x1, y1, bw, bh);
    __syncthreads();

    float* RS = ws + OFF_RS + (b * NN + n) * 1024;
    float* RW = ws + OFF_RW + (b * NN + n) * 1024;
    for (int c = tid; c < 1024; c += 256) {
        int q = c & 31, p = c >> 5;
        float W[9] = {0.f,0.f,0.f,0.f,0.f,0.f,0.f,0.f,0.f};
        float wys[4], wxs[4];
        int iy0s[4], ix0s[4];
        int iymin = 64, ixmin = 64;
#pragma unroll
        for (int s_ = 0; s_ < 4; s_++) {
            int di = s_ >> 1, dj = s_ & 1;
            float y = y1 + ((float)p + 0.25f + 0.5f * (float)di) * bh;
            float x = x1 + ((float)q + 0.25f + 0.5f * (float)dj) * bw;
            float yc = fminf(fmaxf(y, 0.0f), 63.0f);
            float xc = fminf(fmaxf(x, 0.0f), 63.0f);
            int iy0 = (int)floorf(yc), ix0 = (int)floorf(xc);
            wys[s_] = yc - (float)iy0;
            wxs[s_] = xc - (float)ix0;
            iy0s[s_] = iy0; ix0s[s_] = ix0;
            iymin = min(iymin, iy0); ixmin = min(ixmin, ix0);
        }
#pragma unroll
        for (int s_ = 0; s_ < 4; s_++) {
            float wy = wys[s_], wx = wxs[s_];
            int dy = iy0s[s_] - iymin;
            int dx = ix0s[s_] - ixmin;
            bool yt = (iy0s[s_] == 63);
            bool xt = (ix0s[s_] == 63);
            float ay0 = yt ? 1.0f : (1.0f - wy);
            float ay1 = yt ? 0.0f : wy;
            float ax0 = xt ? 1.0f : (1.0f - wx);
            float ax1 = xt ? 0.0f : wx;
            float r0 = dy ? 0.0f : ay0;
            float r1 = dy ? ay0  : ay1;
            float r2 = dy ? ay1  : 0.0f;
            float c0 = dx ? 0.0f : ax0;
            float c1 = dx ? ax0  : ax1;
            float c2 = dx ? ax1  : 0.0f;
            W[0] += r0 * c0; W[1] += r0 * c1; W[2] += r0 * c2;
            W[3] += r1 * c0; W[4] += r1 * c1; W[5] += r1 * c2;
            W[6] += r2 * c0; W[7] += r2 * c1; W[8] += r2 * c2;
        }
        int base = iymin * 64 + ixmin;
        float ss = 0.f, ww = 0.f;
#pragma unroll
        for (int k = 0; k < 9; k++) {
            if (W[k] != 0.0f) {
                float wk = W[k] * 0.25f;
                int off = base + (k / 3) * 64 + (k % 3);
                ss += wk * gsm[off];
                ww += wk * gwm[off];
            }
        }
        RS[c] = ss;
        RW[c] = ww;
        rwsm[c] = ww;
    }
    __syncthreads();

    // fw max over valid pixels (bbox-restricted scan, rw grid in LDS)
    int h0  = max(0, (int)floorf(y1 - 0.5f * bh) - 1);
    int h1  = min(63, (int)ceilf(y1 + 32.5f * bh) + 1);
    int wq0 = max(0, (int)floorf(x1 - 0.5f * bw) - 1);
    int wq1 = min(63, (int)ceilf(x1 + 32.5f * bw) + 1);
    int Wd = wq1 - wq0 + 1;
    int tot = Wd * (h1 - h0 + 1);
    float lm = FMIN_F;
    for (int i = tid; i < tot; i += 256) {
        int h  = h0 + i / Wd;
        int wp = wq0 + i % Wd;
        float ry = ((float)h - y1) / bh - 0.5f;
        float rx = ((float)wp - x1) / bw - 0.5f;
        if (ry > -1.0f && ry < 32.0f && rx > -1.0f && rx < 32.0f) {
            float yc = fminf(fmaxf(ry, 0.0f), 31.0f);
            float xc = fminf(fmaxf(rx, 0.0f), 31.0f);
            int iy0 = (int)floorf(yc), ix0 = (int)floorf(xc);
            int iy1 = min(iy0 + 1, 31), ix1 = min(ix0 + 1, 31);
            float wy = yc - (float)iy0, wx = xc - (float)ix0;
            float fwv = (1.f - wy) * (1.f - wx) * rwsm[iy0 * 32 + ix0]
                      + (1.f - wy) * wx        * rwsm[iy0 * 32 + ix1]
                      + wy * (1.f - wx)        * rwsm[iy1 * 32 + ix0]
                      + wy * wx                * rwsm[iy1 * 32 + ix1];
            lm = fmaxf(lm, fwv);
        }
    }
#pragma unroll
    for (int off = 32; off > 0; off >>= 1)
        lm = fmaxf(lm, __shfl_down(lm, off, 64));
    if ((tid & 63) == 0) red[tid >> 6] = lm;
    __syncthreads();
    if (tid == 0) {
        float mx = fmaxf(fmaxf(red[0], red[1]), fmaxf(red[2], red[3]));
        MP[b * NM + 1 + n] = encf(fmaxf(mx, 0.0f));
    }
}

// Kernel 3: fused MLP + inline-z softmax + final gather. Unpool recomputed
// directly from nhs with separable 1-D weights (exact reference math, fp32).
// r5: weights folded ONCE per (pixel, active-ROI) in the z-phase using named
// scalars (no runtime-indexed locals -> no scratch), stored to LDS; the
// gather phase (8 px x 40 lanes) just reads broadcast weights.
__global__ void k_final(const float* __restrict__ nhs, const float* __restrict__ attn,
                        const float* __restrict__ boxes, const int* __restrict__ masks,
                        const int* __restrict__ perm,
                        const float* __restrict__ w1, const float* __restrict__ b1,
                        const float* __restrict__ w2, const float* __restrict__ b2,
                        const float* __restrict__ ws, float* __restrict__ out) {
    __shared__ float mpg[NM], hb[NM], scal[32], w0tab[8];
    __shared__ float wtab[8][NN][8];   // per (pixel, pos): WY[4]*wn, WX[4]
    __shared__ int   btab[8][NN];      // rb*64+cb
    __shared__ int   acnt[8];
    int t = threadIdx.x;
    int idx0 = blockIdx.x * 8;         // all 8 pixels share the same b
    int b = idx0 >> 12;

    // hoist the attn loads: independent of all shared state, latency hides
    // under the MLP + softmax phases.
    int pid = t / 40;
    int v = t - pid * 40;
    int idx = idx0 + pid;
    const float4* at4 = (const float4*)attn;
    float4 a0 = at4[(size_t)idx * 80 + v * 2];
    float4 a1 = at4[(size_t)idx * 80 + v * 2 + 1];

    if (t < 8) acnt[t] = 0;
    if (t < NM) {
        unsigned e = ((const unsigned*)(ws + OFF_MP))[b * NM + ((t == 0) ? 0 : 1 + perm[t - 1])];
        mpg[t] = decf(e);
    }
    __syncthreads();
    if (t < NM) {
        float a = b1[t];
#pragma unroll
        for (int k = 0; k < NM; k++) a += mpg[k] * w1[k * NM + t];
        hb[t] = fmaxf(a, 0.0f);
    }
    __syncthreads();
    if (t < NM) {
        float a = b2[t];
#pragma unroll
        for (int k = 0; k < NM; k++) a += hb[k] * w2[k * NM + t];
        float sig = 1.0f / (1.0f + expf(-a));
        if (t == 0) scal[0] = sig;
        else        scal[1 + perm[t - 1]] = sig;
    }
    __syncthreads();

    // softmax with inline z + weight fold: one thread per (pixel, m)
    if (t < 256) {
        int pg = t >> 5, m = t & 31;
        int pix = (idx0 + pg) & 4095;
        float zz = FMIN_F;
        float x1, y1, bw, bh, fy = 0.f, fx = 0.f;
        int iy0 = 0, ix0 = 0, iy1 = 0, ix1 = 0;
        if (m == 0) {
            float fwv = ws[OFF_AWRED + b * HW + pix];
            bool fg = (ws[OFF_ASUM + b * HW + pix] != 0.0f);
            zz = fg ? fwv * scal[0] : FMIN_F;
        } else if (m < NM) {
            int n = m - 1;
            if (masks[b * NN + n]) {
                get_box(boxes, b, n, x1, y1, bw, bh);
                int h = pix >> 6, wp = pix & 63;
                float ry = ((float)h - y1) / bh - 0.5f;
                float rx = ((float)wp - x1) / bw - 0.5f;
                bool valid = (ry > -1.0f) && (ry < 32.0f) && (rx > -1.0f) && (rx < 32.0f);
                if (valid) {
                    float yc = fminf(fmaxf(ry, 0.0f), 31.0f);
                    float xc = fminf(fmaxf(rx, 0.0f), 31.0f);
                    iy0 = (int)floorf(yc); ix0 = (int)floorf(xc);
                    iy1 = min(iy0 + 1, 31); ix1 = min(ix0 + 1, 31);
                    fy = yc - (float)iy0; fx = xc - (float)ix0;
                    float w00 = (1.f - fy) * (1.f - fx), w01 = (1.f - fy) * fx;
                    float w10 = fy * (1.f - fx), w11 = fy * fx;
                    const float* rw = ws + OFF_RW + (b * NN + n) * 1024;
                    const float* rs = ws + OFF_RS + (b * NN + n) * 1024;
                    float fwv = w00 * rw[iy0 * 32 + ix0] + w01 * rw[iy0 * 32 + ix1]
                              + w10 * rw[iy1 * 32 + ix0] + w11 * rw[iy1 * 32 + ix1];
                    float su  = w00 * rs[iy0 * 32 + ix0] + w01 * rs[iy0 * 32 + ix1]
                              + w10 * rs[iy1 * 32 + ix0] + w11 * rs[iy1 * 32 + ix1];
                    if (su != 0.0f) zz = fwv * scal[m];
                }
            }
        }
        float mx = zz;
#pragma unroll
        for (int off = 16; off > 0; off >>= 1)
            mx = fmaxf(mx, __shfl_xor(mx, off, 64));
        float e = (m < NM) ? expf(zz - mx) : 0.0f;
        float s = e;
#pragma unroll
        for (int off = 16; off > 0; off >>= 1)
            s += __shfl_xor(s, off, 64);
        if (m < NM) {
            float w = e / s;
            if (m == 0) {
                w0tab[pg] = w;
            } else if (w != 0.0f) {
                // w != 0 implies mask && valid && su != 0 -> box vars defined.
                int pos = atomicAdd(&acnt[pg], 1);
                float ya00 = fminf(fmaxf(y1 + ((float)iy0 + 0.25f) * bh, 0.f), 63.f);
                float ya01 = fminf(fmaxf(y1 + ((float)iy0 + 0.75f) * bh, 0.f), 63.f);
                float ya10 = fminf(fmaxf(y1 + ((float)iy1 + 0.25f) * bh, 0.f), 63.f);
                float ya11 = fminf(fmaxf(y1 + ((float)iy1 + 0.75f) * bh, 0.f), 63.f);
                float xa00 = fminf(fmaxf(x1 + ((float)ix0 + 0.25f) * bw, 0.f), 63.f);
                float xa01 = fminf(fmaxf(x1 + ((float)ix0 + 0.75f) * bw, 0.f), 63.f);
                float xa10 = fminf(fmaxf(x1 + ((float)ix1 + 0.25f) * bw, 0.f), 63.f);
                float xa11 = fminf(fmaxf(x1 + ((float)ix1 + 0.75f) * bw, 0.f), 63.f);
                int rb = (int)floorf(ya00);    // positions monotone -> min first
                int cb = (int)floorf(xa00);
                float wy0 = 0.f, wy1 = 0.f, wy2 = 0.f, wy3 = 0.f;
                float wx0 = 0.f, wx1 = 0.f, wx2 = 0.f, wx3 = 0.f;
                float cy0 = 0.5f * (1.0f - fy), cy1 = 0.5f * fy;
                float cx0 = 0.5f * (1.0f - fx), cx1 = 0.5f * fx;
                // named-scalar accumulation (no runtime-indexed locals)
#define ACCY(pos_, val_) { int d_ = (pos_) - rb; float v_ = (val_); \
    wy0 += (d_ == 0) ? v_ : 0.f; wy1 += (d_ == 1) ? v_ : 0.f; \
    wy2 += (d_ == 2) ? v_ : 0.f; wy3 += (d_ == 3) ? v_ : 0.f; }
#define ACCX(pos_, val_) { int d_ = (pos_) - cb; float v_ = (val_); \
    wx0 += (d_ == 0) ? v_ : 0.f; wx1 += (d_ == 1) ? v_ : 0.f; \
    wx2 += (d_ == 2) ? v_ : 0.f; wx3 += (d_ == 3) ? v_ : 0.f; }
                {
                    int i; float f;
                    i = (int)floorf(ya00); f = ya00 - (float)i;
                    ACCY(i, cy0 * (1.f - f)); ACCY(min(i + 1, 63), cy0 * f);
                    i = (int)floorf(ya01); f = ya01 - (float)i;
                    ACCY(i, cy0 * (1.f - f)); ACCY(min(i + 1, 63), cy0 * f);
                    i = (int)floorf(ya10); f = ya10 - (float)i;
                    ACCY(i, cy1 * (1.f - f)); ACCY(min(i + 1, 63), cy1 * f);
                    i = (int)floorf(ya11); f = ya11 - (float)i;
                    ACCY(i, cy1 * (1.f - f)); ACCY(min(i + 1, 63), cy1 * f);
                    i = (int)floorf(xa00); f = xa00 - (float)i;
                    ACCX(i, cx0 * (1.f - f)); ACCX(min(i + 1, 63), cx0 * f);
                    i = (int)floorf(xa01); f = xa01 - (float)i;
                    ACCX(i, cx0 * (1.f - f)); ACCX(min(i + 1, 63), cx0 * f);
                    i = (int)floorf(xa10); f = xa10 - (float)i;
                    ACCX(i, cx1 * (1.f - f)); ACCX(min(i + 1, 63), cx1 * f);
                    i = (int)floorf(xa11); f = xa11 - (float)i;
                    ACCX(i, cx1 * (1.f - f)); ACCX(min(i + 1, 63), cx1 * f);
                }
#undef ACCY
#undef ACCX
                float* wt = &wtab[pg][pos][0];
                wt[0] = wy0 * w; wt[1] = wy1 * w; wt[2] = wy2 * w; wt[3] = wy3 * w;
                wt[4] = wx0;     wt[5] = wx1;     wt[6] = wx2;     wt[7] = wx3;
                btab[pg][pos] = rb * 64 + cb;
            }
        }
    }
    __syncthreads();

    int pix = idx & 4095;
    float w0 = w0tab[pid];
    float4 acc0, acc1;
    acc0.x = a0.x * w0; acc0.y = a0.y * w0; acc0.z = a0.z * w0; acc0.w = a0.w * w0;
    acc1.x = a1.x * w0; acc1.y = a1.y * w0; acc1.z = a1.z * w0; acc1.w = a1.w * w0;
    const float4* fb4 = (const float4*)(nhs + (size_t)b * HW * NC);
    int na = acnt[pid];
    (void)pix;
    for (int k = 0; k < na; k++) {
        const float* wt = &wtab[pid][k][0];
        int bc = btab[pid][k];
        float wyv_[4] = { wt[0], wt[1], wt[2], wt[3] };   // unrolled use only
        float wxv_[4] = { wt[4], wt[5], wt[6], wt[7] };
#pragma unroll
        for (int r = 0; r < 4; r++) {
            float wy = wyv_[r];
            if (wy == 0.f) continue;
            int rowoff = bc + r * 64;
#pragma unroll
            for (int cc = 0; cc < 4; cc++) {
                float wgt = wy * wxv_[cc];
                if (wgt == 0.f) continue;
                int off = (rowoff + cc) * 80 + v * 2;
                float4 f0 = fb4[off];
                float4 f1 = fb4[off + 1];
                acc0.x += wgt * f0.x; acc0.y += wgt * f0.y;
                acc0.z += wgt * f0.z; acc0.w += wgt * f0.w;
                acc1.x += wgt * f1.x; acc1.y += wgt * f1.y;
                acc1.z += wgt * f1.z; acc1.w += wgt * f1.w;
            }
        }
    }
    nfloat4 nv0 = { acc0.x, acc0.y, acc0.z, acc0.w };
    nfloat4 nv1 = { acc1.x, acc1.y, acc1.z, acc1.w };
    __builtin_nontemporal_store(nv0, ((nfloat4*)out) + (size_t)idx * 80 + v * 2);
    __builtin_nontemporal_store(nv1, ((nfloat4*)out) + (size_t)idx * 80 + v * 2 + 1);
}

extern "C" void kernel_launch(void* const* d_in, const int* in_sizes, int n_in,
                              void* d_out, int out_size, void* d_ws, size_t ws_size,
                              hipStream_t stream) {
    const float* nhs   = (const float*)d_in[0];
    const float* attn  = (const float*)d_in[1];
    const float* boxes = (const float*)d_in[2];
    const int*   masks = (const int*)d_in[3];
    const int*   perm  = (const int*)d_in[4];
    const float* wred  = (const float*)d_in[5];
    const float* w1    = (const float*)d_in[6];
    const float* b1    = (const float*)d_in[7];
    const float* w2    = (const float*)d_in[8];
    const float* b2    = (const float*)d_in[9];
    float* out = (float*)d_out;
    float* ws = (float*)d_ws;

    k_reduce<<<GRID_RED, 320, 0, stream>>>(nhs, attn, wred, ws);
    k_grids<<<NB * NN + NB, 256, 0, stream>>>(boxes, masks, ws);
    k_final<<<NB * HW / 8, 320, 0, stream>>>(nhs, attn, boxes, masks, perm,
                                             w1, b1, w2, b2, ws, out);
}